// Round 1
// baseline (350.423 us; speedup 1.0000x reference)
//
#include <hip/hip_runtime.h>
#include <stddef.h>

#define BB 32
#define NN 1024
#define DD 128
#define HH 128
#define NEG_BIAS 9000000000000000.0f

using f32x4 = __attribute__((ext_vector_type(4))) float;
using f16x8 = __attribute__((ext_vector_type(8))) _Float16;
using f16x4 = __attribute__((ext_vector_type(4))) _Float16;

// ---------------- Projection kernel: q,k (row-major f16), vT (transposed f16) ----------
// grid: 1024 blocks (32 rows each), 256 threads.
__global__ __launch_bounds__(256) void proj_kernel(
    const float* __restrict__ x,
    const float* __restrict__ Wv, const float* __restrict__ bv,
    const float* __restrict__ Wk, const float* __restrict__ bk,
    const float* __restrict__ Wq, const float* __restrict__ bq,
    _Float16* __restrict__ qo, _Float16* __restrict__ ko, _Float16* __restrict__ vTo)
{
    __shared__ float xs[32 * 128];     // 16 KB
    __shared__ float Wl[128 * 128];    // 64 KB
    const int tid  = threadIdx.x;
    const int row0 = blockIdx.x * 32;           // flat row in [0, B*N)
    const int b    = row0 >> 10;
    const int n0   = row0 & 1023;

    // stage x tile (coalesced float4)
    {
        const f32x4* xg = (const f32x4*)(x + (size_t)row0 * 128);
        f32x4* xs4 = (f32x4*)xs;
        for (int i = tid; i < 1024; i += 256) xs4[i] = xg[i];
    }

    const int h4 = tid & 31;   // h chunk: h = h4*4 .. h4*4+3
    const int rg = tid >> 5;   // row group: rows rg*4 .. rg*4+3

    for (int p = 0; p < 3; ++p) {
        const float* W    = (p == 0) ? Wv : ((p == 1) ? Wk : Wq);
        const float* bias = (p == 0) ? bv : ((p == 1) ? bk : bq);
        __syncthreads();                         // previous pass done reading Wl / xs stored
        {
            const f32x4* Wg = (const f32x4*)W;
            f32x4* Wl4 = (f32x4*)Wl;
            for (int i = tid; i < 4096; i += 256) Wl4[i] = Wg[i];
        }
        __syncthreads();

        const f32x4* xs4 = (const f32x4*)xs;
        const f32x4* Wl4 = (const f32x4*)Wl;
        f32x4 bias4 = ((const f32x4*)bias)[h4];
        f32x4 acc[4];
        #pragma unroll
        for (int r = 0; r < 4; ++r) acc[r] = bias4;

        #pragma unroll 4
        for (int d4 = 0; d4 < 32; ++d4) {
            f32x4 w0 = Wl4[(d4 * 4 + 0) * 32 + h4];
            f32x4 w1 = Wl4[(d4 * 4 + 1) * 32 + h4];
            f32x4 w2 = Wl4[(d4 * 4 + 2) * 32 + h4];
            f32x4 w3 = Wl4[(d4 * 4 + 3) * 32 + h4];
            #pragma unroll
            for (int r = 0; r < 4; ++r) {
                f32x4 xv = xs4[(rg * 4 + r) * 32 + d4];
                acc[r] += xv[0] * w0 + xv[1] * w1 + xv[2] * w2 + xv[3] * w3;
            }
        }

        #pragma unroll
        for (int r = 0; r < 4; ++r) {
            int row = rg * 4 + r;
            f32x4 a = acc[r];
            f16x4 hv;
            #pragma unroll
            for (int j = 0; j < 4; ++j) hv[j] = (_Float16)fmaxf(a[j], 0.0f);
            if (p == 0) {
                // vT[b][h][n]
                #pragma unroll
                for (int j = 0; j < 4; ++j)
                    vTo[(size_t)b * HH * NN + (size_t)(h4 * 4 + j) * NN + n0 + row] = hv[j];
            } else if (p == 1) {
                *(f16x4*)&ko[(size_t)(row0 + row) * 128 + h4 * 4] = hv;
            } else {
                *(f16x4*)&qo[(size_t)(row0 + row) * 128 + h4 * 4] = hv;
            }
        }
    }
}

// ---------------- Fused attention kernel (flash-style, f16 MFMA) ----------------------
// grid: (N/64, B); block 256 threads = 4 waves; wave w handles rows i0 = bx*64 + w*16.
__global__ __launch_bounds__(256) void attn_kernel(
    const _Float16* __restrict__ q, const _Float16* __restrict__ k,
    const _Float16* __restrict__ vT, const float* __restrict__ mask,
    float* __restrict__ out)
{
    __shared__ _Float16 ks[32 * 136];      // K-tile rows, padded stride 136 (8704 B)
    __shared__ _Float16 vs[128 * 40];      // vT tile [h][j], padded stride 40 (10240 B)
    __shared__ _Float16 ps[4][16 * 40];    // per-wave P tile [i][j], stride 40 (5120 B)

    const int tid = threadIdx.x;
    const int w   = tid >> 6;
    const int ln  = tid & 63;
    const int qd  = ln >> 4;       // quad 0..3
    const int l16 = ln & 15;
    const int b   = blockIdx.y;
    const int i0  = blockIdx.x * 64 + w * 16;

    // Q A-fragments (rows i0+l16, k = t*32 + qd*8 + j)
    f16x8 qf[4];
    {
        const _Float16* qrow = q + ((size_t)b * NN + i0 + l16) * 128;
        #pragma unroll
        for (int t = 0; t < 4; ++t)
            qf[t] = *(const f16x8*)(qrow + t * 32 + qd * 8);
    }

    f32x4 acc[8];
    #pragma unroll
    for (int hc = 0; hc < 8; ++hc) acc[hc] = (f32x4)(0.0f);
    float m_i[4], l_i[4];
    #pragma unroll
    for (int r = 0; r < 4; ++r) { m_i[r] = -__builtin_inff(); l_i[r] = 0.0f; }

    const float* mrow = mask + (size_t)b * NN * NN;
    // mask rows: i = i0 + qd*4 + r ; cols j = j0 + c*16 + l16
    float mk[8];
    #pragma unroll
    for (int c = 0; c < 2; ++c)
        #pragma unroll
        for (int r = 0; r < 4; ++r)
            mk[c * 4 + r] = mrow[(size_t)(i0 + qd * 4 + r) * NN + c * 16 + l16];

    const _Float16* kbase = k + ((size_t)b * NN) * 128;
    const _Float16* vbase = vT + (size_t)b * HH * NN;

    for (int jt = 0; jt < 32; ++jt) {
        const int j0 = jt * 32;
        __syncthreads();   // all waves done reading ks/vs from previous tile
        // stage K-tile: 32 rows x 128 f16
        for (int c = tid; c < 512; c += 256) {
            int row = c >> 4, col = c & 15;
            *(f16x8*)&ks[row * 136 + col * 8] = *(const f16x8*)(kbase + (size_t)(j0 + row) * 128 + col * 8);
        }
        // stage vT-tile: 128 rows x 32 f16
        for (int c = tid; c < 512; c += 256) {
            int row = c >> 2, col = c & 3;
            *(f16x8*)&vs[row * 40 + col * 8] = *(const f16x8*)(vbase + (size_t)row * NN + j0 + col * 8);
        }
        __syncthreads();

        // prefetch next tile's mask
        float mk2[8];
        if (jt < 31) {
            #pragma unroll
            for (int c = 0; c < 2; ++c)
                #pragma unroll
                for (int r = 0; r < 4; ++r)
                    mk2[c * 4 + r] = mrow[(size_t)(i0 + qd * 4 + r) * NN + (j0 + 32) + c * 16 + l16];
        } else {
            #pragma unroll
            for (int i = 0; i < 8; ++i) mk2[i] = 0.0f;
        }

        // S = Q * K^T  (two 16x16 col-chunks)
        f32x4 s[2];
        s[0] = (f32x4)(0.0f); s[1] = (f32x4)(0.0f);
        #pragma unroll
        for (int c = 0; c < 2; ++c) {
            #pragma unroll
            for (int t = 0; t < 4; ++t) {
                f16x8 bf = *(const f16x8*)&ks[(c * 16 + l16) * 136 + t * 32 + qd * 8];
                s[c] = __builtin_amdgcn_mfma_f32_16x16x32_f16(qf[t], bf, s[c], 0, 0, 0);
            }
        }

        // mask + online softmax (rows split across quads: row = qd*4 + r)
        float scale[4];
        #pragma unroll
        for (int r = 0; r < 4; ++r) {
            float m0 = mk[r], m1 = mk[4 + r];
            float lg0 = s[0][r] * m0 - NEG_BIAS * (1.0f - m0);
            float lg1 = s[1][r] * m1 - NEG_BIAS * (1.0f - m1);
            float mx = fmaxf(lg0, lg1);
            mx = fmaxf(mx, __shfl_xor(mx, 1));
            mx = fmaxf(mx, __shfl_xor(mx, 2));
            mx = fmaxf(mx, __shfl_xor(mx, 4));
            mx = fmaxf(mx, __shfl_xor(mx, 8));
            float mnew = fmaxf(m_i[r], mx);
            float p0 = __expf(lg0 - mnew);
            float p1 = __expf(lg1 - mnew);
            float rs = p0 + p1;
            rs += __shfl_xor(rs, 1);
            rs += __shfl_xor(rs, 2);
            rs += __shfl_xor(rs, 4);
            rs += __shfl_xor(rs, 8);
            float sc = __expf(m_i[r] - mnew);
            l_i[r] = l_i[r] * sc + rs;
            m_i[r] = mnew;
            scale[r] = sc;
            ps[w][(qd * 4 + r) * 40 + l16]      = (_Float16)p0;
            ps[w][(qd * 4 + r) * 40 + 16 + l16] = (_Float16)p1;
        }

        // rescale accumulators
        #pragma unroll
        for (int hc = 0; hc < 8; ++hc) {
            #pragma unroll
            for (int r = 0; r < 4; ++r) acc[hc][r] *= scale[r];
        }

        // PV: A = P (from per-wave LDS, A-layout), B = vT rows
        f16x8 pa = *(const f16x8*)&ps[w][l16 * 40 + qd * 8];
        #pragma unroll
        for (int hc = 0; hc < 8; ++hc) {
            f16x8 bf = *(const f16x8*)&vs[(hc * 16 + l16) * 40 + qd * 8];
            acc[hc] = __builtin_amdgcn_mfma_f32_16x16x32_f16(pa, bf, acc[hc], 0, 0, 0);
        }

        #pragma unroll
        for (int i = 0; i < 8; ++i) mk[i] = mk2[i];
    }

    // epilogue: out = acc / l
    float inv[4];
    #pragma unroll
    for (int r = 0; r < 4; ++r) inv[r] = 1.0f / l_i[r];
    #pragma unroll
    for (int hc = 0; hc < 8; ++hc) {
        #pragma unroll
        for (int r = 0; r < 4; ++r) {
            out[((size_t)b * NN + i0 + qd * 4 + r) * 128 + hc * 16 + l16] = acc[hc][r] * inv[r];
        }
    }
}

extern "C" void kernel_launch(void* const* d_in, const int* in_sizes, int n_in,
                              void* d_out, int out_size, void* d_ws, size_t ws_size,
                              hipStream_t stream) {
    const float* x    = (const float*)d_in[0];
    const float* mask = (const float*)d_in[1];
    const float* Wv   = (const float*)d_in[2];
    const float* bv   = (const float*)d_in[3];
    const float* Wk   = (const float*)d_in[4];
    const float* bk   = (const float*)d_in[5];
    const float* Wq   = (const float*)d_in[6];
    const float* bq   = (const float*)d_in[7];
    float* out = (float*)d_out;

    const size_t BNH = (size_t)BB * NN * HH;   // 4,194,304 elements
    _Float16* ws  = (_Float16*)d_ws;
    _Float16* vTb = ws;                 // [B][H][N]
    _Float16* kb  = ws + BNH;           // [B][N][H]
    _Float16* qb  = ws + 2 * BNH;       // [B][N][H]

    proj_kernel<<<1024, 256, 0, stream>>>(x, Wv, bv, Wk, bk, Wq, bq, qb, kb, vTb);
    attn_kernel<<<dim3(16, 32), 256, 0, stream>>>(qb, kb, vTb, mask, out);
}